// Round 14
// baseline (309.565 us; speedup 1.0000x reference)
//
#include <hip/hip_runtime.h>
#include <math.h>

#define NB 4
#define L 4096
#define D 64
// ws layout (ushorts): qh[16384][64] | K hi: per batch [cq 8][col 4096][8 bf16]
#define WS_K  1048576
#define KBS   262144
// Q pre-scale: 1/TEMPERATURE * log2(e)  -> scores in log2 units (monotone)
#define QSCALE 0.1803368801111243f

typedef __attribute__((ext_vector_type(8))) short short8;   // 8 bf16 = 4 VGPRs
typedef __attribute__((ext_vector_type(4))) float floatx4;

// fp32 -> bf16 RNE
static __device__ inline unsigned short f2bf(float x) {
    unsigned int u = __builtin_bit_cast(unsigned int, x);
    return (unsigned short)((u + (0x7FFFu + ((u >> 16) & 1u))) >> 16);
}

// ---- pre-pass: Q (scaled) and K fp32 -> bf16 hi plane in d_ws
__global__ __launch_bounds__(256)
void convert_kernel(const float* __restrict__ qg, const float* __restrict__ kg,
                    unsigned short* __restrict__ ws) {
    unsigned int i = blockIdx.x * 256 + threadIdx.x;       // 524288 threads
    if (i < 262144) {                                      // Q: 262144 float4
        float4 qv = ((const float4*)qg)[i];
        ushort4 h;
        h.x = f2bf(qv.x * QSCALE); h.y = f2bf(qv.y * QSCALE);
        h.z = f2bf(qv.z * QSCALE); h.w = f2bf(qv.w * QSCALE);
        *(ushort4*)&ws[i * 4] = h;
    } else {                                               // K: 262144 float4
        unsigned int j = i - 262144;
        float4 kv = ((const float4*)kg)[j];
        ushort4 h;
        h.x = f2bf(kv.x); h.y = f2bf(kv.y); h.z = f2bf(kv.z); h.w = f2bf(kv.w);
        unsigned int bcol = j >> 4;                        // b*4096 + col
        unsigned int f4   = j & 15;
        unsigned int b    = bcol >> 12, col = bcol & 4095;
        unsigned int cq   = f4 >> 1, half = f4 & 1;
        size_t base = WS_K + (size_t)b * KBS + ((size_t)cq * 4096 + col) * 8 + half * 4;
        *(ushort4*)&ws[base] = h;
    }
}

// ---- tagged top-k primitives ------------------------------------------------
// Scores carry their column in the low 12 mantissa bits (cleared first):
// tag = 4095-col for s>=0, col for s<0  => float order == (score, lowest col).
static __device__ inline void ins5(float d[5], float t) {
    float n0 = fmaxf(d[0], t);
    float n1 = __builtin_amdgcn_fmed3f(t, d[0], d[1]);
    float n2 = __builtin_amdgcn_fmed3f(t, d[1], d[2]);
    float n3 = __builtin_amdgcn_fmed3f(t, d[2], d[3]);
    float n4 = __builtin_amdgcn_fmed3f(t, d[3], d[4]);
    d[0] = n0; d[1] = n1; d[2] = n2; d[3] = n3; d[4] = n4;
}

// Merge a sorted-descending 8-list o into sorted d (top-8 of union).
static __device__ inline void merge8(float d[8], const float o[8]) {
#pragma unroll
    for (int j = 0; j < 8; ++j) {
        float t = o[j];
        float carry = d[j];
        d[j] = fmaxf(d[j], t);
#pragma unroll
        for (int k = j + 1; k < 8; ++k) {
            float pk = d[k];
            d[k] = __builtin_amdgcn_fmed3f(t, carry, d[k]);
            carry = pk;
        }
    }
}

// 16 rows/block, 8 col-eighth waves (512 cols x 32 iters), grid 1024 x 512
// -> 32 waves/CU (8/SIMD) under __launch_bounds__(512, 8).
// NT zero-fill: in the PHASE-ROTATED regime each block needs its 0.5 MB K
// panel L2-resident across its whole pass; the 268 MB zero-fill stream must
// not write-allocate-evict it. (r1's NT null was the lockstep regime, where
// the live K window was a shared 128 KB slice and eviction was free.)
__global__ __launch_bounds__(512, 8)
void sparse_attn_kernel(const unsigned short* __restrict__ ws,
                        const float* __restrict__ qg,
                        const float* __restrict__ kg,
                        const float* __restrict__ vg,
                        float* __restrict__ outg) {
    __shared__ float smv[8][16][8];     // [col-eighth][row][slot]  (4 KB)

    const int tid  = threadIdx.x;
    const int lane = tid & 63;
    const int wid  = tid >> 6;          // col eighth 0..7
    const int c16  = lane & 15;
    const int quad = lane >> 4;

    // XCD swizzle: consecutive sblk on one XCD (128 blocks/XCD)
    const int sblk  = (blockIdx.x & 7) * 128 + (blockIdx.x >> 3);
    const int qbase = sblk * 16;        // 16 rows per block
    const int b     = qbase >> 12;
    const int phase = sblk & 31;        // loop-phase rotation within XCD

    const unsigned short* qh   = ws;
    const unsigned short* kbat = ws + WS_K + (size_t)b * KBS;
    const float* vb = vg + (size_t)b * L * D;
    float* attng = outg + (size_t)NB * L * D;

    // ---- Q fragment (loop-invariant), B operand of the swapped MFMA
    const int qrow = qbase + c16;
    const short8 a0h = *(const short8*)&qh[(size_t)qrow * 64 + quad * 8];
    const short8 a1h = *(const short8*)&qh[(size_t)qrow * 64 + 32 + quad * 8];

    float tv[5];                        // tagged top-5 for row c16 (sorted desc)
#pragma unroll
    for (int i = 0; i < 5; ++i) tv[i] = -INFINITY;

    // Per-wave 512-col slice; K fragment base pointers (b128, coalesced).
    const int colq = wid * 512;
    const unsigned short* bp0 = kbat + ((size_t)(quad)     * 4096 + colq + c16) * 8;
    const unsigned short* bp1 = kbat + ((size_t)(4 + quad) * 4096 + colq + c16) * 8;
    const floatx4 zv = {0.f, 0.f, 0.f, 0.f};
    const int colb0 = colq + quad * 4;  // r=0 col base (+ cg*16)

    // ---- barrier-free hot loop: 32 groups of 16 columns, phase-rotated
#pragma unroll 2
    for (int cg0 = 0; cg0 < 32; ++cg0) {
        int cg = cg0 + phase;
        cg = (cg >= 32) ? cg - 32 : cg;             // rotate, wrap

        const int off = cg * 128;                   // 16 cols * 8 ushorts
        short8 b0h = *(const short8*)(bp0 + off);
        short8 b1h = *(const short8*)(bp1 + off);
        floatx4 acc = {0.f, 0.f, 0.f, 0.f};
        acc = __builtin_amdgcn_mfma_f32_16x16x32_bf16(b0h, a0h, acc, 0, 0, 0);
        acc = __builtin_amdgcn_mfma_f32_16x16x32_bf16(b1h, a1h, acc, 0, 0, 0);

        // zero-fill one float4 of this wave's 512-col x 16-row attn slice
        // (bijective over the 32 rotated iterations). NONTEMPORAL: keep the
        // streaming write from evicting the L2-resident K panel.
        {
            int idx = cg * 64 + lane;               // [0, 2048)
            __builtin_nontemporal_store(zv, (floatx4*)&attng[
                (size_t)(qbase + (idx >> 7)) * L + colq + (idx & 127) * 4]);
        }

        // cols r=0..3: col = colb0 + cg*16 + r (base ≡ 0 mod 4 -> cx_r = cxb^r)
        const int cxb = (colb0 + cg * 16) ^ 4095;
#pragma unroll
        for (int r = 0; r < 4; ++r) {
            int si  = __builtin_bit_cast(int, (float)acc[r]);
            int tag = (cxb ^ r) ^ ((si >> 31) & 4095);  // s<0: flips to col
            int ti  = (si & 0xFFFFF000) | tag;
            ins5(tv, __builtin_bit_cast(float, ti));
        }
    }

    // ---- stage A: widen to 8 slots, butterfly-merge across the 4 quads.
    // Per-lane top-5 (of 128) + top-8-of-union preserves the true top-5
    // candidate set w.h.p. (a loss needs ~10 sigma of bf16 noise).
    float e[8];
#pragma unroll
    for (int i = 0; i < 5; ++i) e[i] = tv[i];
#pragma unroll
    for (int i = 5; i < 8; ++i) e[i] = -INFINITY;
#pragma unroll
    for (int m = 16; m <= 32; m <<= 1) {
        float o[8];
#pragma unroll
        for (int i = 0; i < 8; ++i) o[i] = __shfl_xor(e[i], m, 64);
        merge8(e, o);
    }

    // ---- stage B: quad-0 lanes deposit this wave's 16 per-row lists
    if (quad == 0) {
#pragma unroll
        for (int i = 0; i < 8; ++i) smv[wid][c16][i] = e[i];
    }
    __syncthreads();    // also drains all zero-fill stores (vmcnt(0) pre-barrier)

    // ---- stage C (16x parallel): waves 0-3, quad handles row quad*4+wid
    if (wid < 4) {
        const int rowl = quad * 4 + wid;
        float lv[8];
#pragma unroll
        for (int i = 0; i < 8; ++i) lv[i] = smv[0][rowl][i];
#pragma unroll
        for (int f = 1; f < 8; ++f) {
            float o[8];
#pragma unroll
            for (int i = 0; i < 8; ++i) o[i] = smv[f][rowl][i];
            merge8(lv, o);
        }

        // unpack cols from tags (positive score => tag was 4095-col)
        unsigned int ic[8];
#pragma unroll
        for (int j = 0; j < 8; ++j) {
            int t = __builtin_bit_cast(int, lv[j]);
            ic[j] = (unsigned)((t & 4095) ^ (t >= 0 ? 4095 : 0));
        }

        const int rowabs = qbase + rowl;

        // exact fp32 scores: two batches of 4 independent k-gathers (keeps
        // live VGPRs inside the 64-reg budget), 4-deep shuffle reduce each.
        const float4 qv = *(const float4*)(qg + (size_t)rowabs * D + c16 * 4);
        float s[8];
#pragma unroll
        for (int batch = 0; batch < 2; ++batch) {
            float4 kv0 = *(const float4*)(kg + ((size_t)(b * L) + ic[batch * 4 + 0]) * D + c16 * 4);
            float4 kv1 = *(const float4*)(kg + ((size_t)(b * L) + ic[batch * 4 + 1]) * D + c16 * 4);
            float4 kv2 = *(const float4*)(kg + ((size_t)(b * L) + ic[batch * 4 + 2]) * D + c16 * 4);
            float4 kv3 = *(const float4*)(kg + ((size_t)(b * L) + ic[batch * 4 + 3]) * D + c16 * 4);
            float p0 = qv.x * kv0.x + qv.y * kv0.y + qv.z * kv0.z + qv.w * kv0.w;
            float p1 = qv.x * kv1.x + qv.y * kv1.y + qv.z * kv1.z + qv.w * kv1.w;
            float p2 = qv.x * kv2.x + qv.y * kv2.y + qv.z * kv2.z + qv.w * kv2.w;
            float p3 = qv.x * kv3.x + qv.y * kv3.y + qv.z * kv3.z + qv.w * kv3.w;
#pragma unroll
            for (int m = 1; m <= 8; m <<= 1) {
                p0 += __shfl_xor(p0, m, 64);
                p1 += __shfl_xor(p1, m, 64);
                p2 += __shfl_xor(p2, m, 64);
                p3 += __shfl_xor(p3, m, 64);
            }
            s[batch * 4 + 0] = p0 * QSCALE;
            s[batch * 4 + 1] = p1 * QSCALE;
            s[batch * 4 + 2] = p2 * QSCALE;
            s[batch * 4 + 3] = p3 * QSCALE;
        }

        // exact top-5 of the 8 by VALUE (partial selection sort). Ties need
        // no col ordering: reference weight = max(p - p5 - eps, 0).
#pragma unroll
        for (int j = 0; j < 5; ++j)
#pragma unroll
            for (int k = j + 1; k < 8; ++k) {
                bool sw = s[k] > s[j];
                float ts = sw ? s[k] : s[j];
                s[k] = sw ? s[j] : s[k];  s[j] = ts;
                unsigned int tc2 = sw ? ic[k] : ic[j];
                ic[k] = sw ? ic[j] : ic[k]; ic[j] = tc2;
            }

        // sparsify, Z-free: w_j ∝ max(2^(s_j - s_5) - 1, 0), exact scores
        float u0 = fmaxf(exp2f(s[0] - s[4]) - 1.0f, 0.0f);
        float u1 = fmaxf(exp2f(s[1] - s[4]) - 1.0f, 0.0f);
        float u2 = fmaxf(exp2f(s[2] - s[4]) - 1.0f, 0.0f);
        float u3 = fmaxf(exp2f(s[3] - s[4]) - 1.0f, 0.0f);
        float inv = 1.0f / (u0 + u1 + u2 + u3 + 1e-30f);
        float w0 = u0 * inv, w1 = u1 * inv, w2 = u2 * inv, w3 = u3 * inv;

        const float4 v0 = *(const float4*)(vb + (size_t)ic[0] * D + c16 * 4);
        const float4 v1 = *(const float4*)(vb + (size_t)ic[1] * D + c16 * 4);
        const float4 v2 = *(const float4*)(vb + (size_t)ic[2] * D + c16 * 4);
        const float4 v3 = *(const float4*)(vb + (size_t)ic[3] * D + c16 * 4);
        floatx4 o;
        o.x = w0 * v0.x + w1 * v1.x + w2 * v2.x + w3 * v3.x;
        o.y = w0 * v0.y + w1 * v1.y + w2 * v2.y + w3 * v3.y;
        o.z = w0 * v0.z + w1 * v1.z + w2 * v2.z + w3 * v3.z;
        o.w = w0 * v0.w + w1 * v1.w + w2 * v2.w + w3 * v3.w;
        __builtin_nontemporal_store(o, (floatx4*)(outg + (size_t)rowabs * D + c16 * 4));

        // scatter <=4 nonzeros into the (zeroed) dense attn row
        if (c16 < 4) {
            float wv = c16 == 0 ? w0 : c16 == 1 ? w1 : c16 == 2 ? w2 : w3;
            unsigned int cs = ic[c16];
            if (wv > 0.f)
                attng[(size_t)rowabs * L + cs] = wv;
        }
    }
}

extern "C" void kernel_launch(void* const* d_in, const int* in_sizes, int n_in,
                              void* d_out, int out_size, void* d_ws, size_t ws_size,
                              hipStream_t stream) {
    const float* q = (const float*)d_in[0];
    const float* k = (const float*)d_in[1];
    const float* v = (const float*)d_in[2];
    float* out = (float*)d_out;
    unsigned short* ws = (unsigned short*)d_ws;

    // 1) convert Q (pre-scaled) and K fp32 -> bf16 hi plane in d_ws
    convert_kernel<<<2048, 256, 0, stream>>>(q, k, ws);

    // 2) barrier-free sparse attention: 16 rows x 8 col-eighth waves,
    //    grid 1024 -> 4 blocks/CU x 8 waves = 32 waves/CU (8/SIMD)
    sparse_attn_kernel<<<1024, 512, 0, stream>>>(ws, q, k, v, out);
}

// Round 15
// 298.271 us; speedup vs baseline: 1.0379x; 1.0379x over previous
//
#include <hip/hip_runtime.h>
#include <math.h>

#define NB 4
#define L 4096
#define D 64
// ws layout (ushorts): qh[16384][64] | K hi: per batch [cq 8][col 4096][8 bf16]
#define WS_K  1048576
#define KBS   262144
// Q pre-scale: 1/TEMPERATURE * log2(e)  -> scores in log2 units (monotone)
#define QSCALE 0.1803368801111243f

typedef __attribute__((ext_vector_type(8))) short short8;   // 8 bf16 = 4 VGPRs
typedef __attribute__((ext_vector_type(4))) float floatx4;

// fp32 -> bf16 RNE
static __device__ inline unsigned short f2bf(float x) {
    unsigned int u = __builtin_bit_cast(unsigned int, x);
    return (unsigned short)((u + (0x7FFFu + ((u >> 16) & 1u))) >> 16);
}

// ---- pre-pass: Q (scaled) and K fp32 -> bf16 hi plane in d_ws
__global__ __launch_bounds__(256)
void convert_kernel(const float* __restrict__ qg, const float* __restrict__ kg,
                    unsigned short* __restrict__ ws) {
    unsigned int i = blockIdx.x * 256 + threadIdx.x;       // 524288 threads
    if (i < 262144) {                                      // Q: 262144 float4
        float4 qv = ((const float4*)qg)[i];
        ushort4 h;
        h.x = f2bf(qv.x * QSCALE); h.y = f2bf(qv.y * QSCALE);
        h.z = f2bf(qv.z * QSCALE); h.w = f2bf(qv.w * QSCALE);
        *(ushort4*)&ws[i * 4] = h;
    } else {                                               // K: 262144 float4
        unsigned int j = i - 262144;
        float4 kv = ((const float4*)kg)[j];
        ushort4 h;
        h.x = f2bf(kv.x); h.y = f2bf(kv.y); h.z = f2bf(kv.z); h.w = f2bf(kv.w);
        unsigned int bcol = j >> 4;                        // b*4096 + col
        unsigned int f4   = j & 15;
        unsigned int b    = bcol >> 12, col = bcol & 4095;
        unsigned int cq   = f4 >> 1, half = f4 & 1;
        size_t base = WS_K + (size_t)b * KBS + ((size_t)cq * 4096 + col) * 8 + half * 4;
        *(ushort4*)&ws[base] = h;
    }
}

// ---- tagged top-k primitives ------------------------------------------------
// Scores carry their column in the low 12 mantissa bits (cleared first):
// tag = 4095-col for s>=0, col for s<0  => float order == (score, lowest col).
static __device__ inline void ins5(float d[5], float t) {
    float n0 = fmaxf(d[0], t);
    float n1 = __builtin_amdgcn_fmed3f(t, d[0], d[1]);
    float n2 = __builtin_amdgcn_fmed3f(t, d[1], d[2]);
    float n3 = __builtin_amdgcn_fmed3f(t, d[2], d[3]);
    float n4 = __builtin_amdgcn_fmed3f(t, d[3], d[4]);
    d[0] = n0; d[1] = n1; d[2] = n2; d[3] = n3; d[4] = n4;
}

// Merge a sorted-descending 8-list o into sorted d (top-8 of union).
static __device__ inline void merge8(float d[8], const float o[8]) {
#pragma unroll
    for (int j = 0; j < 8; ++j) {
        float t = o[j];
        float carry = d[j];
        d[j] = fmaxf(d[j], t);
#pragma unroll
        for (int k = j + 1; k < 8; ++k) {
            float pk = d[k];
            d[k] = __builtin_amdgcn_fmed3f(t, carry, d[k]);
            carry = pk;
        }
    }
}

// 16 rows/block, 8 col-eighth waves (512 cols x 32 iters), grid 1024 x 512
// -> 4 blocks/CU x 8 waves = 32 waves/CU (8/SIMD, HW max) under
// __launch_bounds__(512, 8). Plain stores (NT regressed +17us in r14; NT was
// neutral in r1 — regular L2 write path is right for this fill pattern).
__global__ __launch_bounds__(512, 8)
void sparse_attn_kernel(const unsigned short* __restrict__ ws,
                        const float* __restrict__ qg,
                        const float* __restrict__ kg,
                        const float* __restrict__ vg,
                        float* __restrict__ outg) {
    __shared__ float smv[8][16][8];     // [col-eighth][row][slot]  (4 KB)

    const int tid  = threadIdx.x;
    const int lane = tid & 63;
    const int wid  = tid >> 6;          // col eighth 0..7
    const int c16  = lane & 15;
    const int quad = lane >> 4;

    // XCD swizzle: consecutive sblk on one XCD (128 blocks/XCD)
    const int sblk  = (blockIdx.x & 7) * 128 + (blockIdx.x >> 3);
    const int qbase = sblk * 16;        // 16 rows per block
    const int b     = qbase >> 12;
    const int phase = sblk & 31;        // loop-phase rotation within XCD

    const unsigned short* qh   = ws;
    const unsigned short* kbat = ws + WS_K + (size_t)b * KBS;
    const float* vb = vg + (size_t)b * L * D;
    float* attng = outg + (size_t)NB * L * D;

    // ---- Q fragment (loop-invariant), B operand of the swapped MFMA
    const int qrow = qbase + c16;
    const short8 a0h = *(const short8*)&qh[(size_t)qrow * 64 + quad * 8];
    const short8 a1h = *(const short8*)&qh[(size_t)qrow * 64 + 32 + quad * 8];

    float tv[5];                        // tagged top-5 for row c16 (sorted desc)
#pragma unroll
    for (int i = 0; i < 5; ++i) tv[i] = -INFINITY;

    // Per-wave 512-col slice; K fragment base pointers (b128, coalesced).
    const int colq = wid * 512;
    const unsigned short* bp0 = kbat + ((size_t)(quad)     * 4096 + colq + c16) * 8;
    const unsigned short* bp1 = kbat + ((size_t)(4 + quad) * 4096 + colq + c16) * 8;
    const float4 zv = make_float4(0.f, 0.f, 0.f, 0.f);
    const int colb0 = colq + quad * 4;  // r=0 col base (+ cg*16)

    // ---- barrier-free hot loop: 32 groups of 16 columns, phase-rotated
#pragma unroll 2
    for (int cg0 = 0; cg0 < 32; ++cg0) {
        int cg = cg0 + phase;
        cg = (cg >= 32) ? cg - 32 : cg;             // rotate, wrap

        const int off = cg * 128;                   // 16 cols * 8 ushorts
        short8 b0h = *(const short8*)(bp0 + off);
        short8 b1h = *(const short8*)(bp1 + off);
        floatx4 acc = {0.f, 0.f, 0.f, 0.f};
        acc = __builtin_amdgcn_mfma_f32_16x16x32_bf16(b0h, a0h, acc, 0, 0, 0);
        acc = __builtin_amdgcn_mfma_f32_16x16x32_bf16(b1h, a1h, acc, 0, 0, 0);

        // zero-fill one float4 of this wave's 512-col x 16-row attn slice
        // (bijective over the 32 rotated iterations)
        {
            int idx = cg * 64 + lane;               // [0, 2048)
            *(float4*)&attng[(size_t)(qbase + (idx >> 7)) * L + colq + (idx & 127) * 4] = zv;
        }

        // cols r=0..3: col = colb0 + cg*16 + r (base ≡ 0 mod 4 -> cx_r = cxb^r)
        const int cxb = (colb0 + cg * 16) ^ 4095;
#pragma unroll
        for (int r = 0; r < 4; ++r) {
            int si  = __builtin_bit_cast(int, (float)acc[r]);
            int tag = (cxb ^ r) ^ ((si >> 31) & 4095);  // s<0: flips to col
            int ti  = (si & 0xFFFFF000) | tag;
            ins5(tv, __builtin_bit_cast(float, ti));
        }
    }

    // ---- stage A: widen to 8 slots, butterfly-merge across the 4 quads.
    // Per-lane top-5 (of 128) + top-8-of-union preserves the true top-5
    // candidate set w.h.p. (a loss needs ~10 sigma of bf16 noise).
    float e[8];
#pragma unroll
    for (int i = 0; i < 5; ++i) e[i] = tv[i];
#pragma unroll
    for (int i = 5; i < 8; ++i) e[i] = -INFINITY;
#pragma unroll
    for (int m = 16; m <= 32; m <<= 1) {
        float o[8];
#pragma unroll
        for (int i = 0; i < 8; ++i) o[i] = __shfl_xor(e[i], m, 64);
        merge8(e, o);
    }

    // ---- stage B: quad-0 lanes deposit this wave's 16 per-row lists
    if (quad == 0) {
#pragma unroll
        for (int i = 0; i < 8; ++i) smv[wid][c16][i] = e[i];
    }
    __syncthreads();    // also drains all zero-fill stores (vmcnt(0) pre-barrier)

    // ---- stage C (16x parallel): waves 0-3, quad handles row quad*4+wid
    if (wid < 4) {
        const int rowl = quad * 4 + wid;
        float lv[8];
#pragma unroll
        for (int i = 0; i < 8; ++i) lv[i] = smv[0][rowl][i];
#pragma unroll
        for (int f = 1; f < 8; ++f) {
            float o[8];
#pragma unroll
            for (int i = 0; i < 8; ++i) o[i] = smv[f][rowl][i];
            merge8(lv, o);
        }

        // unpack cols from tags (positive score => tag was 4095-col)
        unsigned int ic[8];
#pragma unroll
        for (int j = 0; j < 8; ++j) {
            int t = __builtin_bit_cast(int, lv[j]);
            ic[j] = (unsigned)((t & 4095) ^ (t >= 0 ? 4095 : 0));
        }

        const int rowabs = qbase + rowl;

        // exact fp32 scores: two batches of 4 independent k-gathers (keeps
        // live VGPRs inside the 64-reg budget), 4-deep shuffle reduce each.
        const float4 qv = *(const float4*)(qg + (size_t)rowabs * D + c16 * 4);
        float s[8];
#pragma unroll
        for (int batch = 0; batch < 2; ++batch) {
            float4 kv0 = *(const float4*)(kg + ((size_t)(b * L) + ic[batch * 4 + 0]) * D + c16 * 4);
            float4 kv1 = *(const float4*)(kg + ((size_t)(b * L) + ic[batch * 4 + 1]) * D + c16 * 4);
            float4 kv2 = *(const float4*)(kg + ((size_t)(b * L) + ic[batch * 4 + 2]) * D + c16 * 4);
            float4 kv3 = *(const float4*)(kg + ((size_t)(b * L) + ic[batch * 4 + 3]) * D + c16 * 4);
            float p0 = qv.x * kv0.x + qv.y * kv0.y + qv.z * kv0.z + qv.w * kv0.w;
            float p1 = qv.x * kv1.x + qv.y * kv1.y + qv.z * kv1.z + qv.w * kv1.w;
            float p2 = qv.x * kv2.x + qv.y * kv2.y + qv.z * kv2.z + qv.w * kv2.w;
            float p3 = qv.x * kv3.x + qv.y * kv3.y + qv.z * kv3.z + qv.w * kv3.w;
#pragma unroll
            for (int m = 1; m <= 8; m <<= 1) {
                p0 += __shfl_xor(p0, m, 64);
                p1 += __shfl_xor(p1, m, 64);
                p2 += __shfl_xor(p2, m, 64);
                p3 += __shfl_xor(p3, m, 64);
            }
            s[batch * 4 + 0] = p0 * QSCALE;
            s[batch * 4 + 1] = p1 * QSCALE;
            s[batch * 4 + 2] = p2 * QSCALE;
            s[batch * 4 + 3] = p3 * QSCALE;
        }

        // exact top-5 of the 8 by VALUE (partial selection sort). Ties need
        // no col ordering: reference weight = max(p - p5 - eps, 0).
#pragma unroll
        for (int j = 0; j < 5; ++j)
#pragma unroll
            for (int k = j + 1; k < 8; ++k) {
                bool sw = s[k] > s[j];
                float ts = sw ? s[k] : s[j];
                s[k] = sw ? s[j] : s[k];  s[j] = ts;
                unsigned int tc2 = sw ? ic[k] : ic[j];
                ic[k] = sw ? ic[j] : ic[k]; ic[j] = tc2;
            }

        // sparsify, Z-free: w_j ∝ max(2^(s_j - s_5) - 1, 0), exact scores
        float u0 = fmaxf(exp2f(s[0] - s[4]) - 1.0f, 0.0f);
        float u1 = fmaxf(exp2f(s[1] - s[4]) - 1.0f, 0.0f);
        float u2 = fmaxf(exp2f(s[2] - s[4]) - 1.0f, 0.0f);
        float u3 = fmaxf(exp2f(s[3] - s[4]) - 1.0f, 0.0f);
        float inv = 1.0f / (u0 + u1 + u2 + u3 + 1e-30f);
        float w0 = u0 * inv, w1 = u1 * inv, w2 = u2 * inv, w3 = u3 * inv;

        const float4 v0 = *(const float4*)(vb + (size_t)ic[0] * D + c16 * 4);
        const float4 v1 = *(const float4*)(vb + (size_t)ic[1] * D + c16 * 4);
        const float4 v2 = *(const float4*)(vb + (size_t)ic[2] * D + c16 * 4);
        const float4 v3 = *(const float4*)(vb + (size_t)ic[3] * D + c16 * 4);
        float4 o;
        o.x = w0 * v0.x + w1 * v1.x + w2 * v2.x + w3 * v3.x;
        o.y = w0 * v0.y + w1 * v1.y + w2 * v2.y + w3 * v3.y;
        o.z = w0 * v0.z + w1 * v1.z + w2 * v2.z + w3 * v3.z;
        o.w = w0 * v0.w + w1 * v1.w + w2 * v2.w + w3 * v3.w;
        *(float4*)(outg + (size_t)rowabs * D + c16 * 4) = o;

        // scatter <=4 nonzeros into the (zeroed) dense attn row
        if (c16 < 4) {
            float wv = c16 == 0 ? w0 : c16 == 1 ? w1 : c16 == 2 ? w2 : w3;
            unsigned int cs = ic[c16];
            if (wv > 0.f)
                attng[(size_t)rowabs * L + cs] = wv;
        }
    }
}

extern "C" void kernel_launch(void* const* d_in, const int* in_sizes, int n_in,
                              void* d_out, int out_size, void* d_ws, size_t ws_size,
                              hipStream_t stream) {
    const float* q = (const float*)d_in[0];
    const float* k = (const float*)d_in[1];
    const float* v = (const float*)d_in[2];
    float* out = (float*)d_out;
    unsigned short* ws = (unsigned short*)d_ws;

    // 1) convert Q (pre-scaled) and K fp32 -> bf16 hi plane in d_ws
    convert_kernel<<<2048, 256, 0, stream>>>(q, k, ws);

    // 2) barrier-free sparse attention: 16 rows x 8 col-eighth waves,
    //    grid 1024 -> 4 blocks/CU x 8 waves = 32 waves/CU (8/SIMD)
    sparse_attn_kernel<<<1024, 512, 0, stream>>>(ws, q, k, v, out);
}

// Round 16
// 286.750 us; speedup vs baseline: 1.0796x; 1.0402x over previous
//
#include <hip/hip_runtime.h>
#include <math.h>

#define NB 4
#define L 4096
#define D 64
// ws layout (ushorts): qh[16384][64] | K hi: per batch [cq 8][col 4096][8 bf16]
#define WS_K  1048576
#define KBS   262144
// Q pre-scale: 1/TEMPERATURE * log2(e)  -> scores in log2 units (monotone)
#define QSCALE 0.1803368801111243f

typedef __attribute__((ext_vector_type(8))) short short8;   // 8 bf16 = 4 VGPRs
typedef __attribute__((ext_vector_type(4))) float floatx4;

// fp32 -> bf16 RNE
static __device__ inline unsigned short f2bf(float x) {
    unsigned int u = __builtin_bit_cast(unsigned int, x);
    return (unsigned short)((u + (0x7FFFu + ((u >> 16) & 1u))) >> 16);
}

// ---- pre-pass: Q (scaled) and K fp32 -> bf16 hi plane in d_ws
__global__ __launch_bounds__(256)
void convert_kernel(const float* __restrict__ qg, const float* __restrict__ kg,
                    unsigned short* __restrict__ ws) {
    unsigned int i = blockIdx.x * 256 + threadIdx.x;       // 524288 threads
    if (i < 262144) {                                      // Q: 262144 float4
        float4 qv = ((const float4*)qg)[i];
        ushort4 h;
        h.x = f2bf(qv.x * QSCALE); h.y = f2bf(qv.y * QSCALE);
        h.z = f2bf(qv.z * QSCALE); h.w = f2bf(qv.w * QSCALE);
        *(ushort4*)&ws[i * 4] = h;
    } else {                                               // K: 262144 float4
        unsigned int j = i - 262144;
        float4 kv = ((const float4*)kg)[j];
        ushort4 h;
        h.x = f2bf(kv.x); h.y = f2bf(kv.y); h.z = f2bf(kv.z); h.w = f2bf(kv.w);
        unsigned int bcol = j >> 4;                        // b*4096 + col
        unsigned int f4   = j & 15;
        unsigned int b    = bcol >> 12, col = bcol & 4095;
        unsigned int cq   = f4 >> 1, half = f4 & 1;
        size_t base = WS_K + (size_t)b * KBS + ((size_t)cq * 4096 + col) * 8 + half * 4;
        *(ushort4*)&ws[base] = h;
    }
}

// ---- tagged top-k primitives ------------------------------------------------
// Scores carry their column in the low 12 mantissa bits (cleared first):
// tag = 4095-col for s>=0, col for s<0  => float order == (score, lowest col).
static __device__ inline void ins5(float d[5], float t) {
    float n0 = fmaxf(d[0], t);
    float n1 = __builtin_amdgcn_fmed3f(t, d[0], d[1]);
    float n2 = __builtin_amdgcn_fmed3f(t, d[1], d[2]);
    float n3 = __builtin_amdgcn_fmed3f(t, d[2], d[3]);
    float n4 = __builtin_amdgcn_fmed3f(t, d[3], d[4]);
    d[0] = n0; d[1] = n1; d[2] = n2; d[3] = n3; d[4] = n4;
}

// Merge a sorted-descending 8-list o into sorted d (top-8 of union).
static __device__ inline void merge8(float d[8], const float o[8]) {
#pragma unroll
    for (int j = 0; j < 8; ++j) {
        float t = o[j];
        float carry = d[j];
        d[j] = fmaxf(d[j], t);
#pragma unroll
        for (int k = j + 1; k < 8; ++k) {
            float pk = d[k];
            d[k] = __builtin_amdgcn_fmed3f(t, carry, d[k]);
            carry = pk;
        }
    }
}

// 16 rows/block, 8 col-eighth waves (512 cols x 32 iters), grid 1024 x 512
// -> 4 blocks/CU x 8 waves = 32 waves/CU (8/SIMD, HW max).
// ZERO-FILL LINEARIZED: each wave fills 2 COMPLETE rows (32 KB contiguous),
// marched sequentially (un-rotated cg0). r4's "hoisted stores = loop time +
// serial drain" is the write-BW-bound signature; the old per-wave pattern
// (2 KB runs, 16 KB jumps, 8192 interleaved streams) plausibly halves
// effective write BW vs the fill kernel's monolithic sweep.
__global__ __launch_bounds__(512, 8)
void sparse_attn_kernel(const unsigned short* __restrict__ ws,
                        const float* __restrict__ qg,
                        const float* __restrict__ kg,
                        const float* __restrict__ vg,
                        float* __restrict__ outg) {
    __shared__ float smv[8][16][8];     // [col-eighth][row][slot]  (4 KB)

    const int tid  = threadIdx.x;
    const int lane = tid & 63;
    const int wid  = tid >> 6;          // col eighth 0..7
    const int c16  = lane & 15;
    const int quad = lane >> 4;

    // XCD swizzle: consecutive sblk on one XCD (128 blocks/XCD)
    const int sblk  = (blockIdx.x & 7) * 128 + (blockIdx.x >> 3);
    const int qbase = sblk * 16;        // 16 rows per block
    const int b     = qbase >> 12;
    const int phase = sblk & 31;        // loop-phase rotation within XCD

    const unsigned short* qh   = ws;
    const unsigned short* kbat = ws + WS_K + (size_t)b * KBS;
    const float* vb = vg + (size_t)b * L * D;
    float* attng = outg + (size_t)NB * L * D;

    // ---- Q fragment (loop-invariant), B operand of the swapped MFMA
    const int qrow = qbase + c16;
    const short8 a0h = *(const short8*)&qh[(size_t)qrow * 64 + quad * 8];
    const short8 a1h = *(const short8*)&qh[(size_t)qrow * 64 + 32 + quad * 8];

    float tv[5];                        // tagged top-5 for row c16 (sorted desc)
#pragma unroll
    for (int i = 0; i < 5; ++i) tv[i] = -INFINITY;

    // Per-wave 512-col slice; K fragment base pointers (b128, coalesced).
    const int colq = wid * 512;
    const unsigned short* bp0 = kbat + ((size_t)(quad)     * 4096 + colq + c16) * 8;
    const unsigned short* bp1 = kbat + ((size_t)(4 + quad) * 4096 + colq + c16) * 8;
    const float4 zv = make_float4(0.f, 0.f, 0.f, 0.f);
    const int colb0 = colq + quad * 4;  // r=0 col base (+ cg*16)

    // This wave's contiguous 2-row (32 KB) zero-fill region, marched linearly.
    float* zfill = attng + (size_t)(qbase + wid * 2) * L + lane * 4;

    // ---- barrier-free hot loop: 32 groups of 16 columns, phase-rotated
#pragma unroll 2
    for (int cg0 = 0; cg0 < 32; ++cg0) {
        int cg = cg0 + phase;
        cg = (cg >= 32) ? cg - 32 : cg;             // rotate, wrap

        const int off = cg * 128;                   // 16 cols * 8 ushorts
        short8 b0h = *(const short8*)(bp0 + off);
        short8 b1h = *(const short8*)(bp1 + off);
        floatx4 acc = {0.f, 0.f, 0.f, 0.f};
        acc = __builtin_amdgcn_mfma_f32_16x16x32_bf16(b0h, a0h, acc, 0, 0, 0);
        acc = __builtin_amdgcn_mfma_f32_16x16x32_bf16(b1h, a1h, acc, 0, 0, 0);

        // zero-fill: strictly sequential 1 KB/wave/iter within the wave's
        // 32 KB region (indexed by cg0, not the rotated cg)
        *(float4*)(zfill + (size_t)cg0 * 256) = zv;

        // cols r=0..3: col = colb0 + cg*16 + r (base ≡ 0 mod 4 -> cx_r = cxb^r)
        const int cxb = (colb0 + cg * 16) ^ 4095;
#pragma unroll
        for (int r = 0; r < 4; ++r) {
            int si  = __builtin_bit_cast(int, (float)acc[r]);
            int tag = (cxb ^ r) ^ ((si >> 31) & 4095);  // s<0: flips to col
            int ti  = (si & 0xFFFFF000) | tag;
            ins5(tv, __builtin_bit_cast(float, ti));
        }
    }

    // ---- stage A: widen to 8 slots, butterfly-merge across the 4 quads.
    // Per-lane top-5 (of 128) + top-8-of-union preserves the true top-5
    // candidate set w.h.p. (a loss needs ~10 sigma of bf16 noise).
    float e[8];
#pragma unroll
    for (int i = 0; i < 5; ++i) e[i] = tv[i];
#pragma unroll
    for (int i = 5; i < 8; ++i) e[i] = -INFINITY;
#pragma unroll
    for (int m = 16; m <= 32; m <<= 1) {
        float o[8];
#pragma unroll
        for (int i = 0; i < 8; ++i) o[i] = __shfl_xor(e[i], m, 64);
        merge8(e, o);
    }

    // ---- stage B: quad-0 lanes deposit this wave's 16 per-row lists
    if (quad == 0) {
#pragma unroll
        for (int i = 0; i < 8; ++i) smv[wid][c16][i] = e[i];
    }
    __syncthreads();    // also drains all zero-fill stores (vmcnt(0) pre-barrier)

    // ---- stage C (16x parallel): waves 0-3, quad handles row quad*4+wid
    if (wid < 4) {
        const int rowl = quad * 4 + wid;
        float lv[8];
#pragma unroll
        for (int i = 0; i < 8; ++i) lv[i] = smv[0][rowl][i];
#pragma unroll
        for (int f = 1; f < 8; ++f) {
            float o[8];
#pragma unroll
            for (int i = 0; i < 8; ++i) o[i] = smv[f][rowl][i];
            merge8(lv, o);
        }

        // unpack cols from tags (positive score => tag was 4095-col)
        unsigned int ic[8];
#pragma unroll
        for (int j = 0; j < 8; ++j) {
            int t = __builtin_bit_cast(int, lv[j]);
            ic[j] = (unsigned)((t & 4095) ^ (t >= 0 ? 4095 : 0));
        }

        const int rowabs = qbase + rowl;

        // exact fp32 scores: two batches of 4 independent k-gathers (keeps
        // live VGPRs inside the 64-reg budget), 4-deep shuffle reduce each.
        const float4 qv = *(const float4*)(qg + (size_t)rowabs * D + c16 * 4);
        float s[8];
#pragma unroll
        for (int batch = 0; batch < 2; ++batch) {
            float4 kv0 = *(const float4*)(kg + ((size_t)(b * L) + ic[batch * 4 + 0]) * D + c16 * 4);
            float4 kv1 = *(const float4*)(kg + ((size_t)(b * L) + ic[batch * 4 + 1]) * D + c16 * 4);
            float4 kv2 = *(const float4*)(kg + ((size_t)(b * L) + ic[batch * 4 + 2]) * D + c16 * 4);
            float4 kv3 = *(const float4*)(kg + ((size_t)(b * L) + ic[batch * 4 + 3]) * D + c16 * 4);
            float p0 = qv.x * kv0.x + qv.y * kv0.y + qv.z * kv0.z + qv.w * kv0.w;
            float p1 = qv.x * kv1.x + qv.y * kv1.y + qv.z * kv1.z + qv.w * kv1.w;
            float p2 = qv.x * kv2.x + qv.y * kv2.y + qv.z * kv2.z + qv.w * kv2.w;
            float p3 = qv.x * kv3.x + qv.y * kv3.y + qv.z * kv3.z + qv.w * kv3.w;
#pragma unroll
            for (int m = 1; m <= 8; m <<= 1) {
                p0 += __shfl_xor(p0, m, 64);
                p1 += __shfl_xor(p1, m, 64);
                p2 += __shfl_xor(p2, m, 64);
                p3 += __shfl_xor(p3, m, 64);
            }
            s[batch * 4 + 0] = p0 * QSCALE;
            s[batch * 4 + 1] = p1 * QSCALE;
            s[batch * 4 + 2] = p2 * QSCALE;
            s[batch * 4 + 3] = p3 * QSCALE;
        }

        // exact top-5 of the 8 by VALUE (partial selection sort). Ties need
        // no col ordering: reference weight = max(p - p5 - eps, 0).
#pragma unroll
        for (int j = 0; j < 5; ++j)
#pragma unroll
            for (int k = j + 1; k < 8; ++k) {
                bool sw = s[k] > s[j];
                float ts = sw ? s[k] : s[j];
                s[k] = sw ? s[j] : s[k];  s[j] = ts;
                unsigned int tc2 = sw ? ic[k] : ic[j];
                ic[k] = sw ? ic[j] : ic[k]; ic[j] = tc2;
            }

        // sparsify, Z-free: w_j ∝ max(2^(s_j - s_5) - 1, 0), exact scores
        float u0 = fmaxf(exp2f(s[0] - s[4]) - 1.0f, 0.0f);
        float u1 = fmaxf(exp2f(s[1] - s[4]) - 1.0f, 0.0f);
        float u2 = fmaxf(exp2f(s[2] - s[4]) - 1.0f, 0.0f);
        float u3 = fmaxf(exp2f(s[3] - s[4]) - 1.0f, 0.0f);
        float inv = 1.0f / (u0 + u1 + u2 + u3 + 1e-30f);
        float w0 = u0 * inv, w1 = u1 * inv, w2 = u2 * inv, w3 = u3 * inv;

        const float4 v0 = *(const float4*)(vb + (size_t)ic[0] * D + c16 * 4);
        const float4 v1 = *(const float4*)(vb + (size_t)ic[1] * D + c16 * 4);
        const float4 v2 = *(const float4*)(vb + (size_t)ic[2] * D + c16 * 4);
        const float4 v3 = *(const float4*)(vb + (size_t)ic[3] * D + c16 * 4);
        float4 o;
        o.x = w0 * v0.x + w1 * v1.x + w2 * v2.x + w3 * v3.x;
        o.y = w0 * v0.y + w1 * v1.y + w2 * v2.y + w3 * v3.y;
        o.z = w0 * v0.z + w1 * v1.z + w2 * v2.z + w3 * v3.z;
        o.w = w0 * v0.w + w1 * v1.w + w2 * v2.w + w3 * v3.w;
        *(float4*)(outg + (size_t)rowabs * D + c16 * 4) = o;

        // scatter <=4 nonzeros into the (zeroed) dense attn row
        if (c16 < 4) {
            float wv = c16 == 0 ? w0 : c16 == 1 ? w1 : c16 == 2 ? w2 : w3;
            unsigned int cs = ic[c16];
            if (wv > 0.f)
                attng[(size_t)rowabs * L + cs] = wv;
        }
    }
}

extern "C" void kernel_launch(void* const* d_in, const int* in_sizes, int n_in,
                              void* d_out, int out_size, void* d_ws, size_t ws_size,
                              hipStream_t stream) {
    const float* q = (const float*)d_in[0];
    const float* k = (const float*)d_in[1];
    const float* v = (const float*)d_in[2];
    float* out = (float*)d_out;
    unsigned short* ws = (unsigned short*)d_ws;

    // 1) convert Q (pre-scaled) and K fp32 -> bf16 hi plane in d_ws
    convert_kernel<<<2048, 256, 0, stream>>>(q, k, ws);

    // 2) barrier-free sparse attention: 16 rows x 8 col-eighth waves,
    //    grid 1024 -> 4 blocks/CU x 8 waves = 32 waves/CU (8/SIMD)
    sparse_attn_kernel<<<1024, 512, 0, stream>>>(ws, q, k, v, out);
}